// Round 3
// baseline (405.954 us; speedup 1.0000x reference)
//
#include <hip/hip_runtime.h>

typedef _Float16 f16;
typedef f16 f16x8 __attribute__((ext_vector_type(8)));
typedef f16 f16x2 __attribute__((ext_vector_type(2)));
typedef float f32x4 __attribute__((ext_vector_type(4)));

#define PI_F 3.14159265358979323846f

constexpr int PLANE_ELEMS = 128 * 128 * 16;   // per-plane f32 elems in the INPUT
constexpr int IPLANE = 128 * 128 * 32;        // interleaved f16 elems per axis
constexpr int ILINE = 128 * 32;               // interleaved f16 elems per axis

// LDS tile: 256 rows x 128 halves, XOR-swizzled (T2): half_idx ^= (row&7)<<3
// keeps 16B alignment for 8-half-aligned cols, spreads banks across rows.
__device__ __forceinline__ int swz(int row, int col) {
    return row * 128 + (col ^ ((row & 7) << 3));
}

// ---------------------------------------------------------------------------
// Prep 1: fold basis into W1, f16 weights, interleave lines.
// Feature layout (96): [0..47] plane*line color products (axis-major, ch)
//                      [48..83] enc (d*12 + s*6 + k), [84..86] ray, [87..95] 0
// ---------------------------------------------------------------------------
__global__ void prep_small(const float* __restrict__ W1, const float* __restrict__ basisW,
                           const float* __restrict__ W2, const float* __restrict__ W3,
                           const float* __restrict__ dlines, const float* __restrict__ clines,
                           f16* __restrict__ W1p, f16* __restrict__ W2h, f16* __restrict__ W3p,
                           f16* __restrict__ linesI) {
    int t = blockIdx.x * 256 + threadIdx.x;
    if (t < 128 * 96) {
        int r = t / 96, c = t % 96;
        float v = 0.f;
        if (c < 48) {
            for (int m = 0; m < 27; m++) v += W1[r * 66 + m] * basisW[m * 48 + c];
        } else if (c < 84) {
            v = W1[r * 66 + 30 + (c - 48)];       // enc
        } else if (c < 87) {
            v = W1[r * 66 + 27 + (c - 84)];       // ray
        }
        W1p[t] = (f16)v;
        return;
    }
    t -= 128 * 96;
    if (t < 128 * 128) { W2h[t] = (f16)W2[t]; return; }
    t -= 128 * 128;
    if (t < 16 * 128) {
        int r = t / 128, k = t % 128;
        W3p[t] = (f16)(r < 3 ? W3[r * 128 + k] : 0.f);
        return;
    }
    t -= 16 * 128;
    if (t < 3 * ILINE) {
        int axis = t / ILINE;
        int rem = t % ILINE;
        int l = rem / 32, c = rem % 32;
        float v = (c < 16) ? dlines[axis * 2048 + c * 128 + l]
                           : clines[axis * 2048 + (c - 16) * 128 + l];
        linesI[t] = (f16)v;
    }
}

// ---------------------------------------------------------------------------
// Prep 2: planes -> planesI f16 [axis][y][x][c32] (c<16 density, c>=16 color)
// ---------------------------------------------------------------------------
__global__ void interleave_planes(const float* __restrict__ dplanes,
                                  const float* __restrict__ cplanes,
                                  f16* __restrict__ planesI) {
    __shared__ f16 s[128 * 34];
    int b = blockIdx.x;
    int axis = b >> 7;
    int y = b & 127;
    const float* dsrc = dplanes + (size_t)axis * PLANE_ELEMS + y * 128;
    const float* csrc = cplanes + (size_t)axis * PLANE_ELEMS + y * 128;
    int tid = threadIdx.x;
#pragma unroll
    for (int it = 0; it < 8; it++) {
        int c = it * 2 + (tid >> 7);
        int x = tid & 127;
        s[x * 34 + c]      = (f16)dsrc[(size_t)c * 16384 + x];
        s[x * 34 + 16 + c] = (f16)csrc[(size_t)c * 16384 + x];
    }
    __syncthreads();
    f16* dst = planesI + (size_t)(axis * 128 + y) * (128 * 32);
#pragma unroll
    for (int it = 0; it < 8; it++) {
        int d = it * 256 + tid;
        int x = d >> 4, cp = (d & 15) * 2;
        dst[2 * d]     = s[x * 34 + cp];
        dst[2 * d + 1] = s[x * 34 + cp + 1];
    }
}

// ---------------------------------------------------------------------------
// Main fused kernel. 512 threads (8 waves), 256 points/block.
// Phase 1: thread pair per point (half0: color feats+PE, half1: density/sigma).
// Phase 2: 8 waves, each owns one 16-col n-tile (acc[16] per wave).
// ---------------------------------------------------------------------------
__global__ __launch_bounds__(512, 3) void nerf_main(
    const float* __restrict__ pts, const float* __restrict__ rayu,
    const f16* __restrict__ planesI, const f16* __restrict__ linesI,
    const f16* __restrict__ W1p, const f16* __restrict__ W2h, const f16* __restrict__ W3p,
    const float* __restrict__ b1, const float* __restrict__ b2, const float* __restrict__ b3,
    float* __restrict__ out, int N) {
    __shared__ __align__(16) f16 tile[256 * 128];
    const int tid = threadIdx.x;
    const int half = tid >> 8;       // 0: color/feat,  1: density/sigma
    const int pi = tid & 255;
    const int p0 = blockIdx.x * 256;
    const int p = p0 + pi;

    // ---------------- phase 1 ----------------
    {
        float g0 = pts[3 * p + 0], g1 = pts[3 * p + 1], g2 = pts[3 * p + 2];
        float g[3] = {g0, g1, g2};
        float sigma = 0.f;
#pragma unroll
        for (int i = 0; i < 3; i++) {
            const int m0 = (i == 2) ? 1 : 0;
            const int m1 = (i == 0) ? 1 : 2;
            const int vm = 2 - i;
            float fx = (g[m0] + 1.f) * 0.5f * 127.f;
            float fy = (g[m1] + 1.f) * 0.5f * 127.f;
            float fl = (g[vm] + 1.f) * 0.5f * 127.f;
            int ix0 = min(max((int)floorf(fx), 0), 127); int ix1 = min(ix0 + 1, 127);
            int iy0 = min(max((int)floorf(fy), 0), 127); int iy1 = min(iy0 + 1, 127);
            int il0 = min(max((int)floorf(fl), 0), 127); int il1 = min(il0 + 1, 127);
            float wx = fx - (float)ix0, wy = fy - (float)iy0, wl = fl - (float)il0;
            f16 w00 = (f16)((1.f - wx) * (1.f - wy));
            f16 w01 = (f16)(wx * (1.f - wy));
            f16 w10 = (f16)((1.f - wx) * wy);
            f16 w11 = (f16)(wx * wy);
            f16 wl1 = (f16)(1.f - wl), wlh = (f16)wl;
            const f16* c00 = planesI + ((i * 128 + iy0) * 128 + ix0) * 32;
            const f16* c01 = planesI + ((i * 128 + iy0) * 128 + ix1) * 32;
            const f16* c10 = planesI + ((i * 128 + iy1) * 128 + ix0) * 32;
            const f16* c11 = planesI + ((i * 128 + iy1) * 128 + ix1) * 32;
            const f16* l0 = linesI + (i * 128 + il0) * 32;
            const f16* l1 = linesI + (i * 128 + il1) * 32;
            // half0 handles q=2,3 (color), half1 handles q=0,1 (density)
            const int qb = half ? 0 : 2;
#pragma unroll
            for (int qq = 0; qq < 2; qq++) {
                int q = qb + qq;
                f16x8 v00 = *(const f16x8*)(c00 + 8 * q);
                f16x8 v01 = *(const f16x8*)(c01 + 8 * q);
                f16x8 v10 = *(const f16x8*)(c10 + 8 * q);
                f16x8 v11 = *(const f16x8*)(c11 + 8 * q);
                f16x8 pb = v00 * w00 + v01 * w01 + v10 * w10 + v11 * w11;
                f16x8 lv = *(const f16x8*)(l0 + 8 * q) * wl1 + *(const f16x8*)(l1 + 8 * q) * wlh;
                if (half) {
#pragma unroll
                    for (int e = 0; e < 8; e++) sigma += (float)pb[e] * (float)lv[e];
                } else {
                    *(f16x8*)&tile[swz(pi, 16 * i + 8 * qq)] = pb * lv;
                }
            }
        }
        if (half) {
            out[3 * N + p] = sigma;
        } else {
            float rx = rayu[3 * p + 0], ry = rayu[3 * p + 1], rz = rayu[3 * p + 2];
            float rv[3] = {rx, ry, rz};
            f16 tail[48];
#pragma unroll
            for (int d = 0; d < 3; d++) {
                float f = rv[d] * PI_F;
                float s = __sinf(f), c = __cosf(f);
#pragma unroll
                for (int k = 0; k < 6; k++) {
                    tail[12 * d + k] = (f16)s;
                    tail[12 * d + 6 + k] = (f16)c;
                    float ns = 2.f * s * c;
                    float nc = 1.f - 2.f * s * s;
                    s = ns; c = nc;
                }
            }
            tail[36] = (f16)rx; tail[37] = (f16)ry; tail[38] = (f16)rz;
#pragma unroll
            for (int e = 39; e < 48; e++) tail[e] = (f16)0.f;
#pragma unroll
            for (int j = 0; j < 6; j++)
                *(f16x8*)&tile[swz(pi, 48 + 8 * j)] = *(const f16x8*)&tail[8 * j];
        }
    }
    __syncthreads();

    // ---------------- phase 2: MLP via MFMA (8 waves, 1 n-tile each) --------
    const int w = tid >> 6, l = tid & 63, ar = l & 15, kg = l >> 4;
    const int col = 16 * w + ar;

    f32x4 acc[16];

    // ---- L1: feat[256x96] @ W1p^T -> h1 cols [16w,16w+16) ----
    {
        f16x8 bfr[3];
#pragma unroll
        for (int k = 0; k < 3; k++)
            bfr[k] = *(const f16x8*)(W1p + col * 96 + 32 * k + 8 * kg);
        float bias = b1[col];
#pragma unroll
        for (int m = 0; m < 16; m++) acc[m] = (f32x4){bias, bias, bias, bias};
#pragma unroll
        for (int m = 0; m < 16; m++) {
#pragma unroll
            for (int k = 0; k < 3; k++) {
                f16x8 a = *(const f16x8*)&tile[swz(16 * m + ar, 32 * k + 8 * kg)];
                acc[m] = __builtin_amdgcn_mfma_f32_16x16x32_f16(a, bfr[k], acc[m], 0, 0, 0);
            }
        }
    }
    __syncthreads();
#pragma unroll
    for (int m = 0; m < 16; m++)
#pragma unroll
        for (int j = 0; j < 4; j++) {
            float v = fmaxf(acc[m][j], 0.f);
            float o = __shfl_xor(v, 1);
            if (!(ar & 1)) {
                f16x2 pr = {(f16)v, (f16)o};
                *(f16x2*)&tile[swz(16 * m + 4 * kg + j, col)] = pr;
            }
        }
    __syncthreads();

    // ---- L2: h1[256x128] @ W2^T -> h2 cols [16w,16w+16) ----
    {
        f16x8 bfr[4];
#pragma unroll
        for (int k = 0; k < 4; k++)
            bfr[k] = *(const f16x8*)(W2h + col * 128 + 32 * k + 8 * kg);
        float bias = b2[col];
#pragma unroll
        for (int m = 0; m < 16; m++) acc[m] = (f32x4){bias, bias, bias, bias};
#pragma unroll
        for (int m = 0; m < 16; m++) {
#pragma unroll
            for (int k = 0; k < 4; k++) {
                f16x8 a = *(const f16x8*)&tile[swz(16 * m + ar, 32 * k + 8 * kg)];
                acc[m] = __builtin_amdgcn_mfma_f32_16x16x32_f16(a, bfr[k], acc[m], 0, 0, 0);
            }
        }
    }
    __syncthreads();
#pragma unroll
    for (int m = 0; m < 16; m++)
#pragma unroll
        for (int j = 0; j < 4; j++) {
            float v = fmaxf(acc[m][j], 0.f);
            float o = __shfl_xor(v, 1);
            if (!(ar & 1)) {
                f16x2 pr = {(f16)v, (f16)o};
                *(f16x2*)&tile[swz(16 * m + 4 * kg + j, col)] = pr;
            }
        }
    __syncthreads();

    // ---- L3: h2[256x128] @ W3p^T -> rgb; each wave does 2 m-tiles ----
    {
        f16x8 bfr[4];
#pragma unroll
        for (int k = 0; k < 4; k++)
            bfr[k] = *(const f16x8*)(W3p + ar * 128 + 32 * k + 8 * kg);
        float bias3 = (ar < 3) ? b3[ar] : 0.f;
#pragma unroll
        for (int mm = 0; mm < 2; mm++) {
            int m = 2 * w + mm;
            f32x4 a3 = (f32x4){bias3, bias3, bias3, bias3};
#pragma unroll
            for (int k = 0; k < 4; k++) {
                f16x8 a = *(const f16x8*)&tile[swz(16 * m + ar, 32 * k + 8 * kg)];
                a3 = __builtin_amdgcn_mfma_f32_16x16x32_f16(a, bfr[k], a3, 0, 0, 0);
            }
            if (ar < 3) {
#pragma unroll
                for (int j = 0; j < 4; j++) {
                    int row = p0 + 16 * m + 4 * kg + j;
                    out[3 * row + ar] = 1.f / (1.f + __expf(-a3[j]));
                }
            }
        }
    }
}

extern "C" void kernel_launch(void* const* d_in, const int* in_sizes, int n_in,
                              void* d_out, int out_size, void* d_ws, size_t ws_size,
                              hipStream_t stream) {
    const float* pts    = (const float*)d_in[0];
    const float* rayu   = (const float*)d_in[1];
    const float* dplanes = (const float*)d_in[2];
    const float* dlines  = (const float*)d_in[3];
    const float* cplanes = (const float*)d_in[4];
    const float* clines  = (const float*)d_in[5];
    const float* basisW  = (const float*)d_in[6];
    const float* W1 = (const float*)d_in[7];
    const float* b1 = (const float*)d_in[8];
    const float* W2 = (const float*)d_in[9];
    const float* b2 = (const float*)d_in[10];
    const float* W3 = (const float*)d_in[11];
    const float* b3 = (const float*)d_in[12];
    float* out = (float*)d_out;
    const int N = in_sizes[0] / 3;

    f16* planesI = (f16*)d_ws;                 // 3 * 128*128*32
    f16* linesI = planesI + 3 * IPLANE;        // 3 * 128*32
    f16* W1p = linesI + 3 * ILINE;             // 128*96
    f16* W2h = W1p + 128 * 96;                 // 128*128
    f16* W3p = W2h + 128 * 128;                // 16*128

    prep_small<<<168, 256, 0, stream>>>(W1, basisW, W2, W3, dlines, clines,
                                        W1p, W2h, W3p, linesI);
    interleave_planes<<<384, 256, 0, stream>>>(dplanes, cplanes, planesI);
    nerf_main<<<N / 256, 512, 0, stream>>>(pts, rayu, planesI, linesI,
                                           W1p, W2h, W3p, b1, b2, b3, out, N);
}

// Round 4
// 239.530 us; speedup vs baseline: 1.6948x; 1.6948x over previous
//
#include <hip/hip_runtime.h>

typedef _Float16 f16;
typedef f16 f16x8 __attribute__((ext_vector_type(8)));
typedef float f32x4 __attribute__((ext_vector_type(4)));

#define PI_F 3.14159265358979323846f

constexpr int TP = 128;          // points per block
constexpr int FSTR = 136;        // LDS row stride in f16 (272 B, 16B-aligned)
constexpr int PLANE_ELEMS = 128 * 128 * 16;   // per-plane f32 elems in the INPUT
constexpr int IPLANE = 128 * 128 * 32;        // interleaved f16 elems per axis
constexpr int ILINE = 128 * 32;               // interleaved f16 elems per axis

// ---------------------------------------------------------------------------
// Prep 1 (R2-proven): fold basis into W1, f16 weights, interleave lines.
// Feature layout (96): [0..47] color plane*line products (axis-major, 16 ch)
//                      [48..50] ray, [51..86] enc (12d+6s+k), [87..95] 0
// ---------------------------------------------------------------------------
__global__ void prep_small(const float* __restrict__ W1, const float* __restrict__ basisW,
                           const float* __restrict__ W2, const float* __restrict__ W3,
                           const float* __restrict__ dlines, const float* __restrict__ clines,
                           f16* __restrict__ W1p, f16* __restrict__ W2h, f16* __restrict__ W3p,
                           f16* __restrict__ linesI) {
    int t = blockIdx.x * 256 + threadIdx.x;
    if (t < 128 * 96) {
        int r = t / 96, c = t % 96;
        float v = 0.f;
        if (c < 48) {
            for (int m = 0; m < 27; m++) v += W1[r * 66 + m] * basisW[m * 48 + c];
        } else if (c < 51) {
            v = W1[r * 66 + 27 + (c - 48)];
        } else if (c < 87) {
            v = W1[r * 66 + 30 + (c - 51)];
        }
        W1p[t] = (f16)v;
        return;
    }
    t -= 128 * 96;
    if (t < 128 * 128) { W2h[t] = (f16)W2[t]; return; }
    t -= 128 * 128;
    if (t < 16 * 128) {
        int r = t / 128, k = t % 128;
        W3p[t] = (f16)(r < 3 ? W3[r * 128 + k] : 0.f);
        return;
    }
    t -= 16 * 128;
    if (t < 3 * ILINE) {
        int axis = t / ILINE;
        int rem = t % ILINE;
        int l = rem / 32, c = rem % 32;
        float v = (c < 16) ? dlines[axis * 2048 + c * 128 + l]
                           : clines[axis * 2048 + (c - 16) * 128 + l];
        linesI[t] = (f16)v;
    }
}

// ---------------------------------------------------------------------------
// Prep 2: planes -> planesI f16 [axis][y][x][c32] (c<16 density, c>=16 color)
// ---------------------------------------------------------------------------
__global__ void interleave_planes(const float* __restrict__ dplanes,
                                  const float* __restrict__ cplanes,
                                  f16* __restrict__ planesI) {
    __shared__ f16 s[128 * 34];
    int b = blockIdx.x;
    int axis = b >> 7;
    int y = b & 127;
    const float* dsrc = dplanes + (size_t)axis * PLANE_ELEMS + y * 128;
    const float* csrc = cplanes + (size_t)axis * PLANE_ELEMS + y * 128;
    int tid = threadIdx.x;
#pragma unroll
    for (int it = 0; it < 8; it++) {
        int c = it * 2 + (tid >> 7);
        int x = tid & 127;
        s[x * 34 + c]      = (f16)dsrc[(size_t)c * 16384 + x];
        s[x * 34 + 16 + c] = (f16)csrc[(size_t)c * 16384 + x];
    }
    __syncthreads();
    f16* dst = planesI + (size_t)(axis * 128 + y) * (128 * 32);
#pragma unroll
    for (int it = 0; it < 8; it++) {
        int d = it * 256 + tid;
        int x = d >> 4, cp = (d & 15) * 2;
        dst[2 * d]     = s[x * 34 + cp];
        dst[2 * d + 1] = s[x * 34 + cp + 1];
    }
}

// per-axis gather: density q=0,1 -> returns sigma partial; color q=2,3 -> frow
template <int I>
__device__ __forceinline__ float axis_work(const f16* __restrict__ planesI,
                                           const f16* __restrict__ linesI,
                                           const float* g, f16* frow) {
    constexpr int m0 = (I == 2) ? 1 : 0;
    constexpr int m1 = (I == 0) ? 1 : 2;
    constexpr int vm = 2 - I;
    float fx = (g[m0] + 1.f) * 0.5f * 127.f;
    float fy = (g[m1] + 1.f) * 0.5f * 127.f;
    float fl = (g[vm] + 1.f) * 0.5f * 127.f;
    int ix0 = min(max((int)floorf(fx), 0), 127); int ix1 = min(ix0 + 1, 127);
    int iy0 = min(max((int)floorf(fy), 0), 127); int iy1 = min(iy0 + 1, 127);
    int il0 = min(max((int)floorf(fl), 0), 127); int il1 = min(il0 + 1, 127);
    float wx = fx - (float)ix0, wy = fy - (float)iy0, wl = fl - (float)il0;
    f16 w00 = (f16)((1.f - wx) * (1.f - wy));
    f16 w01 = (f16)(wx * (1.f - wy));
    f16 w10 = (f16)((1.f - wx) * wy);
    f16 w11 = (f16)(wx * wy);
    f16 wl1 = (f16)(1.f - wl), wlh = (f16)wl;
    const f16* c00 = planesI + ((I * 128 + iy0) * 128 + ix0) * 32;
    const f16* c01 = planesI + ((I * 128 + iy0) * 128 + ix1) * 32;
    const f16* c10 = planesI + ((I * 128 + iy1) * 128 + ix0) * 32;
    const f16* c11 = planesI + ((I * 128 + iy1) * 128 + ix1) * 32;
    const f16* l0 = linesI + (I * 128 + il0) * 32;
    const f16* l1 = linesI + (I * 128 + il1) * 32;
    float sigma = 0.f;
#pragma unroll
    for (int q = 0; q < 2; q++) {   // density channels
        f16x8 v00 = *(const f16x8*)(c00 + 8 * q);
        f16x8 v01 = *(const f16x8*)(c01 + 8 * q);
        f16x8 v10 = *(const f16x8*)(c10 + 8 * q);
        f16x8 v11 = *(const f16x8*)(c11 + 8 * q);
        f16x8 pb = v00 * w00 + v01 * w01 + v10 * w10 + v11 * w11;
        f16x8 lv = *(const f16x8*)(l0 + 8 * q) * wl1 + *(const f16x8*)(l1 + 8 * q) * wlh;
#pragma unroll
        for (int e = 0; e < 8; e++) sigma += (float)pb[e] * (float)lv[e];
    }
#pragma unroll
    for (int qq = 0; qq < 2; qq++) {  // color channels
        int q = 2 + qq;
        f16x8 v00 = *(const f16x8*)(c00 + 8 * q);
        f16x8 v01 = *(const f16x8*)(c01 + 8 * q);
        f16x8 v10 = *(const f16x8*)(c10 + 8 * q);
        f16x8 v11 = *(const f16x8*)(c11 + 8 * q);
        f16x8 pb = v00 * w00 + v01 * w01 + v10 * w10 + v11 * w11;
        f16x8 lv = *(const f16x8*)(l0 + 8 * q) * wl1 + *(const f16x8*)(l1 + 8 * q) * wlh;
        *(f16x8*)(frow + 16 * I + 8 * qq) = pb * lv;
    }
    return sigma;
}

// ---------------------------------------------------------------------------
// Main fused kernel. 256 threads (4 waves), 128 points/block (~34 KB LDS ->
// 4 blocks/CU = 16 waves/CU). Phase 1: lane pair per point split BY AXIS.
// Phase 2: R2-proven two-n-chain MFMA MLP, m = 0..7.
// ---------------------------------------------------------------------------
__global__ __launch_bounds__(256, 4) void nerf_main(
    const float* __restrict__ pts, const float* __restrict__ rayu,
    const f16* __restrict__ planesI, const f16* __restrict__ linesI,
    const f16* __restrict__ W1p, const f16* __restrict__ W2h, const f16* __restrict__ W3p,
    const float* __restrict__ b1, const float* __restrict__ b2, const float* __restrict__ b3,
    float* __restrict__ out, int N) {
    __shared__ __align__(16) f16 tile[TP * FSTR];
    const int tid = threadIdx.x;
    const int pi = tid >> 1;          // point within block
    const int sub = tid & 1;          // 0: axes 0,1   1: axis 2 + PE + ray
    const int p0 = blockIdx.x * TP;
    const int p = p0 + pi;

    // ---------------- phase 1 ----------------
    {
        float g[3] = {pts[3 * p + 0], pts[3 * p + 1], pts[3 * p + 2]};
        f16* frow = &tile[pi * FSTR];
        float sigma;
        if (sub == 0) {
            sigma = axis_work<0>(planesI, linesI, g, frow)
                  + axis_work<1>(planesI, linesI, g, frow);
        } else {
            sigma = axis_work<2>(planesI, linesI, g, frow);
            float rx = rayu[3 * p + 0], ry = rayu[3 * p + 1], rz = rayu[3 * p + 2];
            float rv[3] = {rx, ry, rz};
            f16 tail[48];
            tail[0] = (f16)rx; tail[1] = (f16)ry; tail[2] = (f16)rz;
#pragma unroll
            for (int d = 0; d < 3; d++) {
                float f = rv[d] * PI_F;
                float s = __sinf(f), c = __cosf(f);
#pragma unroll
                for (int k = 0; k < 6; k++) {
                    tail[3 + 12 * d + k] = (f16)s;
                    tail[3 + 12 * d + 6 + k] = (f16)c;
                    float ns = 2.f * s * c;
                    float nc = 1.f - 2.f * s * s;
                    s = ns; c = nc;
                }
            }
#pragma unroll
            for (int e = 39; e < 48; e++) tail[e] = (f16)0.f;
#pragma unroll
            for (int j = 0; j < 6; j++)
                *(f16x8*)&tile[pi * FSTR + 48 + 8 * j] = *(const f16x8*)&tail[8 * j];
        }
        sigma += __shfl_xor(sigma, 1);
        if (sub == 0) out[3 * N + p] = sigma;
    }
    __syncthreads();

    // ---------------- phase 2: MLP via MFMA ----------------
    const int w = tid >> 6, l = tid & 63, ar = l & 15, kg = l >> 4;
    const int col0 = 32 * w + ar;
    const int col1 = 32 * w + 16 + ar;

    f32x4 acc[8][2];

    // ---- L1: feat[128x96] @ W1p^T -> h1[128x128] ----
    {
        f16x8 bfr0[3], bfr1[3];
#pragma unroll
        for (int k = 0; k < 3; k++) {
            bfr0[k] = *(const f16x8*)(W1p + col0 * 96 + 32 * k + 8 * kg);
            bfr1[k] = *(const f16x8*)(W1p + col1 * 96 + 32 * k + 8 * kg);
        }
        float bias0 = b1[col0], bias1 = b1[col1];
#pragma unroll
        for (int m = 0; m < 8; m++) {
            acc[m][0] = (f32x4){bias0, bias0, bias0, bias0};
            acc[m][1] = (f32x4){bias1, bias1, bias1, bias1};
        }
#pragma unroll
        for (int m = 0; m < 8; m++) {
            const f16* arow = &tile[(16 * m + ar) * FSTR + 8 * kg];
#pragma unroll
            for (int k = 0; k < 3; k++) {
                f16x8 a = *(const f16x8*)(arow + 32 * k);
                acc[m][0] = __builtin_amdgcn_mfma_f32_16x16x32_f16(a, bfr0[k], acc[m][0], 0, 0, 0);
                acc[m][1] = __builtin_amdgcn_mfma_f32_16x16x32_f16(a, bfr1[k], acc[m][1], 0, 0, 0);
            }
        }
    }
    __syncthreads();
#pragma unroll
    for (int m = 0; m < 8; m++)
#pragma unroll
        for (int j = 0; j < 4; j++) {
            int row = 16 * m + 4 * kg + j;
            tile[row * FSTR + col0] = (f16)fmaxf(acc[m][0][j], 0.f);
            tile[row * FSTR + col1] = (f16)fmaxf(acc[m][1][j], 0.f);
        }
    __syncthreads();

    // ---- L2: h1[128x128] @ W2^T -> h2[128x128] ----
    {
        f16x8 bfr0[4], bfr1[4];
#pragma unroll
        for (int k = 0; k < 4; k++) {
            bfr0[k] = *(const f16x8*)(W2h + col0 * 128 + 32 * k + 8 * kg);
            bfr1[k] = *(const f16x8*)(W2h + col1 * 128 + 32 * k + 8 * kg);
        }
        float bias0 = b2[col0], bias1 = b2[col1];
#pragma unroll
        for (int m = 0; m < 8; m++) {
            acc[m][0] = (f32x4){bias0, bias0, bias0, bias0};
            acc[m][1] = (f32x4){bias1, bias1, bias1, bias1};
        }
#pragma unroll
        for (int m = 0; m < 8; m++) {
            const f16* arow = &tile[(16 * m + ar) * FSTR + 8 * kg];
#pragma unroll
            for (int k = 0; k < 4; k++) {
                f16x8 a = *(const f16x8*)(arow + 32 * k);
                acc[m][0] = __builtin_amdgcn_mfma_f32_16x16x32_f16(a, bfr0[k], acc[m][0], 0, 0, 0);
                acc[m][1] = __builtin_amdgcn_mfma_f32_16x16x32_f16(a, bfr1[k], acc[m][1], 0, 0, 0);
            }
        }
    }
    __syncthreads();
#pragma unroll
    for (int m = 0; m < 8; m++)
#pragma unroll
        for (int j = 0; j < 4; j++) {
            int row = 16 * m + 4 * kg + j;
            tile[row * FSTR + col0] = (f16)fmaxf(acc[m][0][j], 0.f);
            tile[row * FSTR + col1] = (f16)fmaxf(acc[m][1][j], 0.f);
        }
    __syncthreads();

    // ---- L3: h2[128x128] @ W3p^T -> rgb; each wave does 2 m-tiles ----
    {
        f16x8 bfr[4];
#pragma unroll
        for (int k = 0; k < 4; k++)
            bfr[k] = *(const f16x8*)(W3p + ar * 128 + 32 * k + 8 * kg);
        float bias3 = (ar < 3) ? b3[ar] : 0.f;
#pragma unroll
        for (int mm = 0; mm < 2; mm++) {
            int m = 2 * w + mm;
            f32x4 a3 = (f32x4){bias3, bias3, bias3, bias3};
#pragma unroll
            for (int k = 0; k < 4; k++) {
                f16x8 a = *(const f16x8*)&tile[(16 * m + ar) * FSTR + 32 * k + 8 * kg];
                a3 = __builtin_amdgcn_mfma_f32_16x16x32_f16(a, bfr[k], a3, 0, 0, 0);
            }
            if (ar < 3) {
#pragma unroll
                for (int j = 0; j < 4; j++) {
                    int row = p0 + 16 * m + 4 * kg + j;
                    out[3 * row + ar] = 1.f / (1.f + __expf(-a3[j]));
                }
            }
        }
    }
}

extern "C" void kernel_launch(void* const* d_in, const int* in_sizes, int n_in,
                              void* d_out, int out_size, void* d_ws, size_t ws_size,
                              hipStream_t stream) {
    const float* pts    = (const float*)d_in[0];
    const float* rayu   = (const float*)d_in[1];
    const float* dplanes = (const float*)d_in[2];
    const float* dlines  = (const float*)d_in[3];
    const float* cplanes = (const float*)d_in[4];
    const float* clines  = (const float*)d_in[5];
    const float* basisW  = (const float*)d_in[6];
    const float* W1 = (const float*)d_in[7];
    const float* b1 = (const float*)d_in[8];
    const float* W2 = (const float*)d_in[9];
    const float* b2 = (const float*)d_in[10];
    const float* W3 = (const float*)d_in[11];
    const float* b3 = (const float*)d_in[12];
    float* out = (float*)d_out;
    const int N = in_sizes[0] / 3;

    f16* planesI = (f16*)d_ws;                 // 3 * 128*128*32
    f16* linesI = planesI + 3 * IPLANE;        // 3 * 128*32
    f16* W1p = linesI + 3 * ILINE;             // 128*96
    f16* W2h = W1p + 128 * 96;                 // 128*128
    f16* W3p = W2h + 128 * 128;                // 16*128

    prep_small<<<168, 256, 0, stream>>>(W1, basisW, W2, W3, dlines, clines,
                                        W1p, W2h, W3p, linesI);
    interleave_planes<<<384, 256, 0, stream>>>(dplanes, cplanes, planesI);
    nerf_main<<<N / TP, 256, 0, stream>>>(pts, rayu, planesI, linesI,
                                          W1p, W2h, W3p, b1, b2, b3, out, N);
}